// Round 7
// baseline (733.000 us; speedup 1.0000x reference)
//
#include <hip/hip_runtime.h>

typedef __attribute__((ext_vector_type(8))) short bf16x8;
typedef __attribute__((ext_vector_type(4))) float f32x4;

#define HHE 512

__device__ __forceinline__ unsigned short rne_bf16(float f) {
    union { float f; unsigned u; } v; v.f = f;
    unsigned r = v.u + 0x7FFFu + ((v.u >> 16) & 1u);
    return (unsigned short)(r >> 16);
}
__device__ __forceinline__ float bf2f(unsigned short s) {
    union { unsigned u; float f; } v; v.u = ((unsigned)s) << 16; return v.f;
}
__device__ __forceinline__ float sigf(float v)   { return 1.0f / (1.0f + __expf(-v)); }
__device__ __forceinline__ float tanhf_(float v) { return 2.0f / (1.0f + __expf(-2.0f * v)) - 1.0f; }

#define MFMA16(a, b, c) __builtin_amdgcn_mfma_f32_16x16x32_bf16(a, b, c, 0, 0, 0)

#define GLOAD_LDS16(g, l) \
    __builtin_amdgcn_global_load_lds((const __attribute__((address_space(1))) void*)(g), \
                                     (__attribute__((address_space(3))) void*)(l), 16, 0, 0)

// ---------- one-time: pack 4 gate weight matrices into bf16 MFMA B-fragment order
// [gate][jtile(32)][kstep(32)][lane(64)][8] ----------
__global__ __launch_bounds__(256) void pack_w(
    const float* __restrict__ Wi, const float* __restrict__ Wf,
    const float* __restrict__ Wo, const float* __restrict__ Wu,
    unsigned short* __restrict__ wp)
{
    int t    = blockIdx.x * 256 + threadIdx.x;
    int lane = t & 63;
    int fid  = t >> 6;
    int ks   = fid & 31;
    int jt   = (fid >> 5) & 31;
    int g    = fid >> 10;
    const float* W = (g == 0) ? Wi : (g == 1) ? Wf : (g == 2) ? Wo : Wu;
    int row = jt * 16 + (lane & 15);
    int col = ks * 32 + (lane >> 4) * 8;
    const float* src = W + (size_t)row * 1024 + col;
    float4 f0 = *(const float4*)(src);
    float4 f1 = *(const float4*)(src + 4);
    uint4 o;
    o.x = (unsigned)rne_bf16(f0.x) | ((unsigned)rne_bf16(f0.y) << 16);
    o.y = (unsigned)rne_bf16(f0.z) | ((unsigned)rne_bf16(f0.w) << 16);
    o.z = (unsigned)rne_bf16(f1.x) | ((unsigned)rne_bf16(f1.y) << 16);
    o.w = (unsigned)rne_bf16(f1.z) | ((unsigned)rne_bf16(f1.w) << 16);
    ((uint4*)wp)[t] = o;
}

// ---------- one-time: x fp32 -> bf16 ----------
__global__ __launch_bounds__(256) void conv_x(const float* __restrict__ x,
                                              unsigned short* __restrict__ xb)
{
    size_t idx = (size_t)blockIdx.x * 256 + threadIdx.x;
    if (idx >= 2097088) return;
    const float4* p = (const float4*)x + idx * 2;
    float4 f0 = p[0], f1 = p[1];
    uint4 o;
    o.x = (unsigned)rne_bf16(f0.x) | ((unsigned)rne_bf16(f0.y) << 16);
    o.y = (unsigned)rne_bf16(f0.z) | ((unsigned)rne_bf16(f0.w) << 16);
    o.z = (unsigned)rne_bf16(f1.x) | ((unsigned)rne_bf16(f1.y) << 16);
    o.w = (unsigned)rne_bf16(f1.z) | ((unsigned)rne_bf16(f1.w) << 16);
    ((uint4*)xb)[idx] = o;
}

// ---------- leaf level: register path; grid = (jblk 8, mblk) for XCD/weight affinity ----------
__global__ __launch_bounds__(256) void leaf_mfma(
    const unsigned short* __restrict__ xb, const unsigned short* __restrict__ wp,
    const float* __restrict__ bi, const float* __restrict__ bo, const float* __restrict__ bu,
    unsigned short* __restrict__ hw, unsigned short* __restrict__ cw,
    unsigned short* __restrict__ hso,
    int start, int cnt)
{
    const int tid  = threadIdx.x;
    const int lane = tid & 63;
    const int wv   = tid >> 6;
    const int quad = lane >> 4;
    const int ln   = lane & 15;
    const int mb   = blockIdx.y * 64;                 // m in grid.y
    const int jt   = blockIdx.x * 4 + wv;             // j in grid.x (8) -> XCD affinity
    const int j    = jt * 16 + ln;

    int row[4];
    #pragma unroll
    for (int t = 0; t < 4; ++t) {
        int r = mb + t * 16 + ln;
        row[t] = (r < cnt) ? r : (cnt - 1);
    }
    const unsigned short* ax[4];
    #pragma unroll
    for (int t = 0; t < 4; ++t) ax[t] = xb + (size_t)(start + row[t]) * HHE + quad * 8;

    const unsigned short* bwi = wp + ((size_t)(0 * 32 + jt) * 32) * 512 + lane * 8;
    const unsigned short* bwo = wp + ((size_t)(2 * 32 + jt) * 32) * 512 + lane * 8;
    const unsigned short* bwu = wp + ((size_t)(3 * 32 + jt) * 32) * 512 + lane * 8;

    f32x4 zero = {0.f, 0.f, 0.f, 0.f};
    f32x4 acc_i[4], acc_o[4], acc_u[4];
    #pragma unroll
    for (int t = 0; t < 4; ++t) { acc_i[t] = zero; acc_o[t] = zero; acc_u[t] = zero; }

    #pragma unroll 4
    for (int ks = 0; ks < 16; ++ks) {
        bf16x8 a[4];
        #pragma unroll
        for (int t = 0; t < 4; ++t) { a[t] = *(const bf16x8*)ax[t]; ax[t] += 32; }
        bf16x8 b0 = *(const bf16x8*)bwi; bwi += 512;
        bf16x8 b2 = *(const bf16x8*)bwo; bwo += 512;
        bf16x8 b3 = *(const bf16x8*)bwu; bwu += 512;
        #pragma unroll
        for (int t = 0; t < 4; ++t) {
            acc_i[t] = MFMA16(a[t], b0, acc_i[t]);
            acc_o[t] = MFMA16(a[t], b2, acc_o[t]);
            acc_u[t] = MFMA16(a[t], b3, acc_u[t]);
        }
    }

    const float bij = bi[j], boj = bo[j], buj = bu[j];
    #pragma unroll
    for (int t = 0; t < 4; ++t) {
        const int n0 = mb + t * 16 + quad * 4;
        float hv[4];
        #pragma unroll
        for (int r = 0; r < 4; ++r) {
            const int node = n0 + r;
            float gi = sigf(acc_i[t][r] + bij);
            float go = sigf(acc_o[t][r] + boj);
            float gu = tanhf_(acc_u[t][r] + buj);
            float cnv = gi * gu;
            float hnv = go * tanhf_(cnv);
            hv[r] = hnv;
            if (node < cnt) {
                size_t oix = (size_t)node * HHE + j;
                hw[oix] = rne_bf16(hnv);
                cw[oix] = rne_bf16(cnv);
            }
        }
        if (n0 + 1 < cnt) hso[(size_t)(n0 >> 1) * HHE + j]       = rne_bf16(hv[0] + hv[1]);
        if (n0 + 3 < cnt) hso[(size_t)((n0 >> 1) + 1) * HHE + j] = rne_bf16(hv[2] + hv[3]);
    }
}

// ---------- big internal levels (cnt multiple of 64): LDS-staged, double-buffered;
// grid = (jblk 8, mblk) for XCD/weight affinity ----------
__global__ __launch_bounds__(256, 2) void level_v2(
    const unsigned short* __restrict__ xb, const unsigned short* __restrict__ wp,
    const float* __restrict__ bi, const float* __restrict__ bfv,
    const float* __restrict__ bo, const float* __restrict__ bu,
    const unsigned short* __restrict__ hc, const unsigned short* __restrict__ cc,
    const unsigned short* __restrict__ hs,
    unsigned short* __restrict__ hw, unsigned short* __restrict__ cw,
    unsigned short* __restrict__ hso,
    int start, int cnt)
{
    __shared__ __align__(16) unsigned short SH[2 * 3 * 2048];

    const int tid  = threadIdx.x;
    const int lane = tid & 63;
    const int wv   = tid >> 6;
    const int q    = lane >> 4;
    const int ln   = lane & 15;
    const int wm   = wv & 1;
    const int wj   = wv >> 1;
    const int mb   = blockIdx.y * 64;                 // m in grid.y
    const int jt0  = blockIdx.x * 4 + wj * 2;         // j in grid.x (8) -> XCD affinity

    const int srow   = lane >> 2;
    const int gchunk = (lane & 3) ^ ((lane >> 3) & 3);
    const int stage_row = mb + wv * 16 + srow;
    const int rdoff = ((q ^ ((ln >> 1) & 3)) * 8);

    const unsigned short* wpl = wp + (size_t)lane * 8;

    f32x4 zero = {0.f, 0.f, 0.f, 0.f};
    f32x4 acc_i[2][2], acc_f[2][2], acc_o[2][2], acc_u[2][2];
    #pragma unroll
    for (int t = 0; t < 2; ++t)
        #pragma unroll
        for (int ji = 0; ji < 2; ++ji) {
            acc_i[t][ji] = zero; acc_f[t][ji] = zero;
            acc_o[t][ji] = zero; acc_u[t][ji] = zero;
        }

    {
        const unsigned short* g = xb + (size_t)(start + stage_row) * HHE + gchunk * 8;
        GLOAD_LDS16(g, &SH[(0 * 3 + 0) * 2048 + wv * 512]);
    }
    __syncthreads();

    for (int ks = 0; ks < 16; ++ks) {
        const int cur = ks & 1;
        if (ks < 15) {
            const unsigned short* g = xb + (size_t)(start + stage_row) * HHE + (ks + 1) * 32 + gchunk * 8;
            GLOAD_LDS16(g, &SH[((cur ^ 1) * 3 + 0) * 2048 + wv * 512]);
        }
        bf16x8 bfr[4][2];
        #pragma unroll
        for (int g = 0; g < 4; ++g)
            #pragma unroll
            for (int ji = 0; ji < 2; ++ji)
                bfr[g][ji] = *(const bf16x8*)(wpl + ((size_t)((g * 32 + jt0 + ji) * 32 + ks)) * 512);
        bf16x8 a0 = *(const bf16x8*)&SH[(cur * 3 + 0) * 2048 + (wm * 32 + 0 + ln) * 32 + rdoff];
        bf16x8 a1 = *(const bf16x8*)&SH[(cur * 3 + 0) * 2048 + (wm * 32 + 16 + ln) * 32 + rdoff];
        #pragma unroll
        for (int ji = 0; ji < 2; ++ji) {
            acc_i[0][ji] = MFMA16(a0, bfr[0][ji], acc_i[0][ji]);
            acc_i[1][ji] = MFMA16(a1, bfr[0][ji], acc_i[1][ji]);
            acc_f[0][ji] = MFMA16(a0, bfr[1][ji], acc_f[0][ji]);
            acc_f[1][ji] = MFMA16(a1, bfr[1][ji], acc_f[1][ji]);
            acc_o[0][ji] = MFMA16(a0, bfr[2][ji], acc_o[0][ji]);
            acc_o[1][ji] = MFMA16(a1, bfr[2][ji], acc_o[1][ji]);
            acc_u[0][ji] = MFMA16(a0, bfr[3][ji], acc_u[0][ji]);
            acc_u[1][ji] = MFMA16(a1, bfr[3][ji], acc_u[1][ji]);
        }
        __syncthreads();
    }

    f32x4 acc_fl[2][2], acc_fr[2][2];
    #pragma unroll
    for (int t = 0; t < 2; ++t)
        #pragma unroll
        for (int ji = 0; ji < 2; ++ji) { acc_fl[t][ji] = acc_f[t][ji]; acc_fr[t][ji] = acc_f[t][ji]; }

    {
        const unsigned short* gs = hs + (size_t)stage_row * HHE + gchunk * 8;
        const unsigned short* gl = hc + ((size_t)(2 * stage_row)) * HHE + gchunk * 8;
        GLOAD_LDS16(gs, &SH[(0 * 3 + 0) * 2048 + wv * 512]);
        GLOAD_LDS16(gl, &SH[(0 * 3 + 1) * 2048 + wv * 512]);
        GLOAD_LDS16(gl + HHE, &SH[(0 * 3 + 2) * 2048 + wv * 512]);
    }
    __syncthreads();

    for (int ks = 0; ks < 16; ++ks) {
        const int cur = ks & 1;
        if (ks < 15) {
            const unsigned short* gs = hs + (size_t)stage_row * HHE + (ks + 1) * 32 + gchunk * 8;
            const unsigned short* gl = hc + ((size_t)(2 * stage_row)) * HHE + (ks + 1) * 32 + gchunk * 8;
            GLOAD_LDS16(gs, &SH[((cur ^ 1) * 3 + 0) * 2048 + wv * 512]);
            GLOAD_LDS16(gl, &SH[((cur ^ 1) * 3 + 1) * 2048 + wv * 512]);
            GLOAD_LDS16(gl + HHE, &SH[((cur ^ 1) * 3 + 2) * 2048 + wv * 512]);
        }
        bf16x8 bfr[4][2];
        #pragma unroll
        for (int g = 0; g < 4; ++g)
            #pragma unroll
            for (int ji = 0; ji < 2; ++ji)
                bfr[g][ji] = *(const bf16x8*)(wpl + ((size_t)((g * 32 + jt0 + ji) * 32 + 16 + ks)) * 512);
        bf16x8 s0 = *(const bf16x8*)&SH[(cur * 3 + 0) * 2048 + (wm * 32 + 0 + ln) * 32 + rdoff];
        bf16x8 s1 = *(const bf16x8*)&SH[(cur * 3 + 0) * 2048 + (wm * 32 + 16 + ln) * 32 + rdoff];
        bf16x8 l0 = *(const bf16x8*)&SH[(cur * 3 + 1) * 2048 + (wm * 32 + 0 + ln) * 32 + rdoff];
        bf16x8 l1 = *(const bf16x8*)&SH[(cur * 3 + 1) * 2048 + (wm * 32 + 16 + ln) * 32 + rdoff];
        bf16x8 r0 = *(const bf16x8*)&SH[(cur * 3 + 2) * 2048 + (wm * 32 + 0 + ln) * 32 + rdoff];
        bf16x8 r1 = *(const bf16x8*)&SH[(cur * 3 + 2) * 2048 + (wm * 32 + 16 + ln) * 32 + rdoff];
        #pragma unroll
        for (int ji = 0; ji < 2; ++ji) {
            acc_i[0][ji]  = MFMA16(s0, bfr[0][ji], acc_i[0][ji]);
            acc_i[1][ji]  = MFMA16(s1, bfr[0][ji], acc_i[1][ji]);
            acc_o[0][ji]  = MFMA16(s0, bfr[2][ji], acc_o[0][ji]);
            acc_o[1][ji]  = MFMA16(s1, bfr[2][ji], acc_o[1][ji]);
            acc_u[0][ji]  = MFMA16(s0, bfr[3][ji], acc_u[0][ji]);
            acc_u[1][ji]  = MFMA16(s1, bfr[3][ji], acc_u[1][ji]);
            acc_fl[0][ji] = MFMA16(l0, bfr[1][ji], acc_fl[0][ji]);
            acc_fl[1][ji] = MFMA16(l1, bfr[1][ji], acc_fl[1][ji]);
            acc_fr[0][ji] = MFMA16(r0, bfr[1][ji], acc_fr[0][ji]);
            acc_fr[1][ji] = MFMA16(r1, bfr[1][ji], acc_fr[1][ji]);
        }
        __syncthreads();
    }

    #pragma unroll
    for (int ji = 0; ji < 2; ++ji) {
        const int jj = (jt0 + ji) * 16 + ln;
        const float bij = bi[jj], bfj = bfv[jj], boj = bo[jj], buj = bu[jj];
        #pragma unroll
        for (int t = 0; t < 2; ++t) {
            const int n0 = mb + wm * 32 + t * 16 + q * 4;
            float hv[4];
            #pragma unroll
            for (int r = 0; r < 4; ++r) {
                const int node = n0 + r;
                size_t cix = (size_t)(2 * node) * HHE + jj;
                float cl = bf2f(cc[cix]);
                float cr = bf2f(cc[cix + HHE]);
                float gi  = sigf(acc_i[t][ji][r] + bij);
                float gfl = sigf(acc_fl[t][ji][r] + bfj);
                float gfr = sigf(acc_fr[t][ji][r] + bfj);
                float go  = sigf(acc_o[t][ji][r] + boj);
                float gu  = tanhf_(acc_u[t][ji][r] + buj);
                float cnv = gi * gu + gfl * cl + gfr * cr;
                float hnv = go * tanhf_(cnv);
                hv[r] = hnv;
                size_t oix = (size_t)node * HHE + jj;
                hw[oix] = rne_bf16(hnv);
                cw[oix] = rne_bf16(cnv);
            }
            hso[(size_t)(n0 >> 1) * HHE + jj]       = rne_bf16(hv[0] + hv[1]);
            hso[(size_t)((n0 >> 1) + 1) * HHE + jj] = rne_bf16(hv[2] + hv[3]);
        }
    }
}

// ---------- small levels (9..0): register kernel, per-level launch;
// grid = (jblk 8, mchunks) for XCD/weight affinity ----------
__global__ __launch_bounds__(256) void level_reg(
    const unsigned short* __restrict__ xb, const unsigned short* __restrict__ wp,
    const float* __restrict__ bi, const float* __restrict__ bfv,
    const float* __restrict__ bo, const float* __restrict__ bu,
    const unsigned short* __restrict__ hc, const unsigned short* __restrict__ cc,
    const unsigned short* __restrict__ hs,
    unsigned short* __restrict__ hw, unsigned short* __restrict__ cw,
    unsigned short* __restrict__ hso,
    float* __restrict__ f32out,
    int start, int cnt)
{
    const int tid  = threadIdx.x;
    const int lane = tid & 63;
    const int wv   = tid >> 6;
    const int quad = lane >> 4;
    const int ln   = lane & 15;
    const int mb   = blockIdx.y * 64;                 // m in grid.y
    const int jt   = blockIdx.x * 4 + wv;             // j in grid.x (8) -> XCD affinity
    const int j    = jt * 16 + ln;

    int row[4];
    #pragma unroll
    for (int t = 0; t < 4; ++t) {
        int r = mb + t * 16 + ln;
        row[t] = (r < cnt) ? r : (cnt - 1);
    }
    const unsigned short* ax[4];
    #pragma unroll
    for (int t = 0; t < 4; ++t) ax[t] = xb + (size_t)(start + row[t]) * HHE + quad * 8;

    const unsigned short* bw[4];
    #pragma unroll
    for (int g = 0; g < 4; ++g) bw[g] = wp + ((size_t)(g * 32 + jt) * 32) * 512 + lane * 8;

    f32x4 zero = {0.f, 0.f, 0.f, 0.f};
    f32x4 acc_i[4], acc_f[4], acc_o[4], acc_u[4];
    #pragma unroll
    for (int t = 0; t < 4; ++t) { acc_i[t] = zero; acc_f[t] = zero; acc_o[t] = zero; acc_u[t] = zero; }

    #pragma unroll 4
    for (int ks = 0; ks < 16; ++ks) {
        bf16x8 a[4];
        #pragma unroll
        for (int t = 0; t < 4; ++t) { a[t] = *(const bf16x8*)ax[t]; ax[t] += 32; }
        bf16x8 b0 = *(const bf16x8*)bw[0]; bw[0] += 512;
        bf16x8 b1 = *(const bf16x8*)bw[1]; bw[1] += 512;
        bf16x8 b2 = *(const bf16x8*)bw[2]; bw[2] += 512;
        bf16x8 b3 = *(const bf16x8*)bw[3]; bw[3] += 512;
        #pragma unroll
        for (int t = 0; t < 4; ++t) {
            acc_i[t] = MFMA16(a[t], b0, acc_i[t]);
            acc_f[t] = MFMA16(a[t], b1, acc_f[t]);
            acc_o[t] = MFMA16(a[t], b2, acc_o[t]);
            acc_u[t] = MFMA16(a[t], b3, acc_u[t]);
        }
    }

    f32x4 acc_fl[4], acc_fr[4];
    #pragma unroll
    for (int t = 0; t < 4; ++t) { acc_fl[t] = acc_f[t]; acc_fr[t] = acc_f[t]; }

    const unsigned short* as[4];
    const unsigned short* al[4];
    const unsigned short* ar[4];
    #pragma unroll
    for (int t = 0; t < 4; ++t) {
        as[t] = hs + (size_t)row[t] * HHE + quad * 8;
        al[t] = hc + (size_t)(2 * row[t]) * HHE + quad * 8;
        ar[t] = al[t] + HHE;
    }

    #pragma unroll 2
    for (int ks = 0; ks < 16; ++ks) {
        bf16x8 b0 = *(const bf16x8*)bw[0]; bw[0] += 512;
        bf16x8 b1 = *(const bf16x8*)bw[1]; bw[1] += 512;
        bf16x8 b2 = *(const bf16x8*)bw[2]; bw[2] += 512;
        bf16x8 b3 = *(const bf16x8*)bw[3]; bw[3] += 512;
        bf16x8 s[4];
        #pragma unroll
        for (int t = 0; t < 4; ++t) { s[t] = *(const bf16x8*)as[t]; as[t] += 32; }
        #pragma unroll
        for (int t = 0; t < 4; ++t) {
            acc_i[t] = MFMA16(s[t], b0, acc_i[t]);
            acc_o[t] = MFMA16(s[t], b2, acc_o[t]);
            acc_u[t] = MFMA16(s[t], b3, acc_u[t]);
        }
        bf16x8 l[4];
        #pragma unroll
        for (int t = 0; t < 4; ++t) { l[t] = *(const bf16x8*)al[t]; al[t] += 32; }
        #pragma unroll
        for (int t = 0; t < 4; ++t) acc_fl[t] = MFMA16(l[t], b1, acc_fl[t]);
        bf16x8 rr[4];
        #pragma unroll
        for (int t = 0; t < 4; ++t) { rr[t] = *(const bf16x8*)ar[t]; ar[t] += 32; }
        #pragma unroll
        for (int t = 0; t < 4; ++t) acc_fr[t] = MFMA16(rr[t], b1, acc_fr[t]);
    }

    const float bij = bi[j], bfj = bfv[j], boj = bo[j], buj = bu[j];
    #pragma unroll
    for (int t = 0; t < 4; ++t) {
        const int n0 = mb + t * 16 + quad * 4;
        float hv[4];
        #pragma unroll
        for (int r = 0; r < 4; ++r) {
            const int node = n0 + r;
            const int ncl  = (node < cnt) ? node : (cnt - 1);
            size_t cix = (size_t)(2 * ncl) * HHE + j;
            float cl = bf2f(cc[cix]);
            float cr = bf2f(cc[cix + HHE]);
            float gi  = sigf(acc_i[t][r] + bij);
            float gfl = sigf(acc_fl[t][r] + bfj);
            float gfr = sigf(acc_fr[t][r] + bfj);
            float go  = sigf(acc_o[t][r] + boj);
            float gu  = tanhf_(acc_u[t][r] + buj);
            float cnv = gi * gu + gfl * cl + gfr * cr;
            float hnv = go * tanhf_(cnv);
            hv[r] = hnv;
            if (node < cnt) {
                size_t oix = (size_t)node * HHE + j;
                hw[oix] = rne_bf16(hnv);
                cw[oix] = rne_bf16(cnv);
                if (f32out) {
                    f32out[(size_t)node * 1024 + j]       = hnv;
                    f32out[(size_t)node * 1024 + 512 + j] = cnv;
                }
            }
        }
        if (n0 + 1 < cnt) hso[(size_t)(n0 >> 1) * HHE + j]       = rne_bf16(hv[0] + hv[1]);
        if (n0 + 3 < cnt) hso[(size_t)((n0 >> 1) + 1) * HHE + j] = rne_bf16(hv[2] + hv[3]);
    }
}

extern "C" void kernel_launch(void* const* d_in, const int* in_sizes, int n_in,
                              void* d_out, int out_size, void* d_ws, size_t ws_size,
                              hipStream_t stream) {
    const float* x  = (const float*)d_in[0];
    const float* Wi = (const float*)d_in[1];
    const float* bi = (const float*)d_in[2];
    const float* Wf = (const float*)d_in[3];
    const float* bf = (const float*)d_in[4];
    const float* Wo = (const float*)d_in[5];
    const float* bo = (const float*)d_in[6];
    const float* Wu = (const float*)d_in[7];
    const float* bu = (const float*)d_in[8];
    float* out = (float*)d_out;

    unsigned short* xb  = (unsigned short*)d_ws;          // x bf16
    unsigned short* wp  = xb  + 16776704;                 // packed W bf16
    unsigned short* hA  = wp  + 2097152;                  // h ping (16384 rows)
    unsigned short* hB  = hA  + 8388608;                  // h pong ( 8192 rows)
    unsigned short* hs1 = hB  + 4194304;                  // hsum ( 8192 rows)
    unsigned short* hs2 = hs1 + 4194304;                  // hsum ( 4096 rows)
    unsigned short* cA  = hs2 + 2097152;                  // c ping
    unsigned short* cB  = cA  + 8388608;                  // c pong

    pack_w<<<1024, 256, 0, stream>>>(Wi, Wf, Wo, Wu, wp);
    conv_x<<<8192, 256, 0, stream>>>(x, xb);

    // leaf: grid (j=8, m=256) -> XCD k serves weight slice k only
    leaf_mfma<<<dim3(8, 256), 256, 0, stream>>>(xb, wp, bi, bo, bu, hA, cA, hs1, 16383, 16384);

    // big levels: LDS-staged kernel, grid (j=8, m=cnt/64)
    for (int lvl = 13; lvl >= 10; --lvl) {
        int cnt   = 1 << lvl;
        int start = cnt - 1;
        const unsigned short *hc, *cc, *hs;
        unsigned short *hw, *cw, *hso;
        if (lvl & 1) { hc = hA; cc = cA; hs = hs1; hw = hB; cw = cB; hso = hs2; }
        else         { hc = hB; cc = cB; hs = hs2; hw = hA; cw = cA; hso = hs1; }
        level_v2<<<dim3(8, cnt / 64), 256, 0, stream>>>(xb, wp, bi, bf, bo, bu,
                                                        hc, cc, hs, hw, cw, hso, start, cnt);
    }

    // tail levels: plain per-level launches (kernel boundary = cheap coherence)
    for (int lvl = 9; lvl >= 0; --lvl) {
        int cnt   = 1 << lvl;
        int start = cnt - 1;
        const unsigned short *hc, *cc, *hs;
        unsigned short *hw, *cw, *hso;
        if (lvl & 1) { hc = hA; cc = cA; hs = hs1; hw = hB; cw = cB; hso = hs2; }
        else         { hc = hB; cc = cB; hs = hs2; hw = hA; cw = cA; hso = hs1; }
        float* f32out = (lvl == 0) ? out : nullptr;
        level_reg<<<dim3(8, (cnt + 63) / 64), 256, 0, stream>>>(xb, wp, bi, bf, bo, bu,
                                                                hc, cc, hs, hw, cw, hso, f32out,
                                                                start, cnt);
    }
}

// Round 8
// 627.425 us; speedup vs baseline: 1.1683x; 1.1683x over previous
//
#include <hip/hip_runtime.h>

typedef __attribute__((ext_vector_type(8))) short bf16x8;
typedef __attribute__((ext_vector_type(4))) float f32x4;

#define HHE 512

__device__ __forceinline__ unsigned short rne_bf16(float f) {
    union { float f; unsigned u; } v; v.f = f;
    unsigned r = v.u + 0x7FFFu + ((v.u >> 16) & 1u);
    return (unsigned short)(r >> 16);
}
__device__ __forceinline__ float bf2f(unsigned short s) {
    union { unsigned u; float f; } v; v.u = ((unsigned)s) << 16; return v.f;
}
__device__ __forceinline__ float sigf(float v)   { return 1.0f / (1.0f + __expf(-v)); }
__device__ __forceinline__ float tanhf_(float v) { return 2.0f / (1.0f + __expf(-2.0f * v)) - 1.0f; }

#define MFMA16(a, b, c) __builtin_amdgcn_mfma_f32_16x16x32_bf16(a, b, c, 0, 0, 0)

#define GLOAD_LDS16(g, l) \
    __builtin_amdgcn_global_load_lds((const __attribute__((address_space(1))) void*)(g), \
                                     (__attribute__((address_space(3))) void*)(l), 16, 0, 0)

// ---------- one-time: pack 4 gate weight matrices into bf16 MFMA B-fragment order
// [gate][jtile(32)][kstep(32)][lane(64)][8] ----------
__global__ __launch_bounds__(256) void pack_w(
    const float* __restrict__ Wi, const float* __restrict__ Wf,
    const float* __restrict__ Wo, const float* __restrict__ Wu,
    unsigned short* __restrict__ wp)
{
    int t    = blockIdx.x * 256 + threadIdx.x;
    int lane = t & 63;
    int fid  = t >> 6;
    int ks   = fid & 31;
    int jt   = (fid >> 5) & 31;
    int g    = fid >> 10;
    const float* W = (g == 0) ? Wi : (g == 1) ? Wf : (g == 2) ? Wo : Wu;
    int row = jt * 16 + (lane & 15);
    int col = ks * 32 + (lane >> 4) * 8;
    const float* src = W + (size_t)row * 1024 + col;
    float4 f0 = *(const float4*)(src);
    float4 f1 = *(const float4*)(src + 4);
    uint4 o;
    o.x = (unsigned)rne_bf16(f0.x) | ((unsigned)rne_bf16(f0.y) << 16);
    o.y = (unsigned)rne_bf16(f0.z) | ((unsigned)rne_bf16(f0.w) << 16);
    o.z = (unsigned)rne_bf16(f1.x) | ((unsigned)rne_bf16(f1.y) << 16);
    o.w = (unsigned)rne_bf16(f1.z) | ((unsigned)rne_bf16(f1.w) << 16);
    ((uint4*)wp)[t] = o;
}

// ---------- one-time: x fp32 -> bf16 ----------
__global__ __launch_bounds__(256) void conv_x(const float* __restrict__ x,
                                              unsigned short* __restrict__ xb)
{
    size_t idx = (size_t)blockIdx.x * 256 + threadIdx.x;
    if (idx >= 2097088) return;
    const float4* p = (const float4*)x + idx * 2;
    float4 f0 = p[0], f1 = p[1];
    uint4 o;
    o.x = (unsigned)rne_bf16(f0.x) | ((unsigned)rne_bf16(f0.y) << 16);
    o.y = (unsigned)rne_bf16(f0.z) | ((unsigned)rne_bf16(f0.w) << 16);
    o.z = (unsigned)rne_bf16(f1.x) | ((unsigned)rne_bf16(f1.y) << 16);
    o.w = (unsigned)rne_bf16(f1.z) | ((unsigned)rne_bf16(f1.w) << 16);
    ((uint4*)xb)[idx] = o;
}

// ---------- leaf level: register path; grid = (mblk, 8) m-major ----------
__global__ __launch_bounds__(256) void leaf_mfma(
    const unsigned short* __restrict__ xb, const unsigned short* __restrict__ wp,
    const float* __restrict__ bi, const float* __restrict__ bo, const float* __restrict__ bu,
    unsigned short* __restrict__ hw, unsigned short* __restrict__ cw,
    unsigned short* __restrict__ hso,
    int start, int cnt)
{
    const int tid  = threadIdx.x;
    const int lane = tid & 63;
    const int wv   = tid >> 6;
    const int quad = lane >> 4;
    const int ln   = lane & 15;
    const int mb   = blockIdx.x * 64;
    const int jt   = blockIdx.y * 4 + wv;
    const int j    = jt * 16 + ln;

    int row[4];
    #pragma unroll
    for (int t = 0; t < 4; ++t) {
        int r = mb + t * 16 + ln;
        row[t] = (r < cnt) ? r : (cnt - 1);
    }
    const unsigned short* ax[4];
    #pragma unroll
    for (int t = 0; t < 4; ++t) ax[t] = xb + (size_t)(start + row[t]) * HHE + quad * 8;

    const unsigned short* bwi = wp + ((size_t)(0 * 32 + jt) * 32) * 512 + lane * 8;
    const unsigned short* bwo = wp + ((size_t)(2 * 32 + jt) * 32) * 512 + lane * 8;
    const unsigned short* bwu = wp + ((size_t)(3 * 32 + jt) * 32) * 512 + lane * 8;

    f32x4 zero = {0.f, 0.f, 0.f, 0.f};
    f32x4 acc_i[4], acc_o[4], acc_u[4];
    #pragma unroll
    for (int t = 0; t < 4; ++t) { acc_i[t] = zero; acc_o[t] = zero; acc_u[t] = zero; }

    #pragma unroll 4
    for (int ks = 0; ks < 16; ++ks) {
        bf16x8 a[4];
        #pragma unroll
        for (int t = 0; t < 4; ++t) { a[t] = *(const bf16x8*)ax[t]; ax[t] += 32; }
        bf16x8 b0 = *(const bf16x8*)bwi; bwi += 512;
        bf16x8 b2 = *(const bf16x8*)bwo; bwo += 512;
        bf16x8 b3 = *(const bf16x8*)bwu; bwu += 512;
        #pragma unroll
        for (int t = 0; t < 4; ++t) {
            acc_i[t] = MFMA16(a[t], b0, acc_i[t]);
            acc_o[t] = MFMA16(a[t], b2, acc_o[t]);
            acc_u[t] = MFMA16(a[t], b3, acc_u[t]);
        }
    }

    const float bij = bi[j], boj = bo[j], buj = bu[j];
    #pragma unroll
    for (int t = 0; t < 4; ++t) {
        const int n0 = mb + t * 16 + quad * 4;
        float hv[4];
        #pragma unroll
        for (int r = 0; r < 4; ++r) {
            const int node = n0 + r;
            float gi = sigf(acc_i[t][r] + bij);
            float go = sigf(acc_o[t][r] + boj);
            float gu = tanhf_(acc_u[t][r] + buj);
            float cnv = gi * gu;
            float hnv = go * tanhf_(cnv);
            hv[r] = hnv;
            if (node < cnt) {
                size_t oix = (size_t)node * HHE + j;
                hw[oix] = rne_bf16(hnv);
                cw[oix] = rne_bf16(cnv);
            }
        }
        if (n0 + 1 < cnt) hso[(size_t)(n0 >> 1) * HHE + j]       = rne_bf16(hv[0] + hv[1]);
        if (n0 + 3 < cnt) hso[(size_t)((n0 >> 1) + 1) * HHE + j] = rne_bf16(hv[2] + hv[3]);
    }
}

// ---------- big internal levels (cnt multiple of 64): LDS-staged A, double-buffered,
// ping-pong register-prefetched weights; grid = (mblk, 8) m-major ----------
__global__ __launch_bounds__(256) void level_v3(
    const unsigned short* __restrict__ xb, const unsigned short* __restrict__ wp,
    const float* __restrict__ bi, const float* __restrict__ bfv,
    const float* __restrict__ bo, const float* __restrict__ bu,
    const unsigned short* __restrict__ hc, const unsigned short* __restrict__ cc,
    const unsigned short* __restrict__ hs,
    unsigned short* __restrict__ hw, unsigned short* __restrict__ cw,
    unsigned short* __restrict__ hso,
    int start, int cnt)
{
    __shared__ __align__(16) unsigned short SH[2 * 3 * 2048];

    const int tid  = threadIdx.x;
    const int lane = tid & 63;
    const int wv   = tid >> 6;
    const int q    = lane >> 4;
    const int ln   = lane & 15;
    const int wm   = wv & 1;
    const int wj   = wv >> 1;
    const int mb   = blockIdx.x * 64;
    const int jt0  = blockIdx.y * 4 + wj * 2;

    const int srow   = lane >> 2;
    const int gchunk = (lane & 3) ^ ((lane >> 3) & 3);
    const int stage_row = mb + wv * 16 + srow;
    const int rdoff = ((q ^ ((ln >> 1) & 3)) * 8);

    const unsigned short* wpl = wp + (size_t)lane * 8;

    f32x4 zero = {0.f, 0.f, 0.f, 0.f};
    f32x4 acc_i[2][2], acc_f[2][2], acc_o[2][2], acc_u[2][2];
    #pragma unroll
    for (int t = 0; t < 2; ++t)
        #pragma unroll
        for (int ji = 0; ji < 2; ++ji) {
            acc_i[t][ji] = zero; acc_f[t][ji] = zero;
            acc_o[t][ji] = zero; acc_u[t][ji] = zero;
        }

    bf16x8 WA[4][2], WB[4][2];

    // W fragment loader: absolute ks index 0..31
    auto loadW = [&](bf16x8 (&W)[4][2], int ksabs) {
        #pragma unroll
        for (int g = 0; g < 4; ++g)
            #pragma unroll
            for (int ji = 0; ji < 2; ++ji)
                W[g][ji] = *(const bf16x8*)(wpl + ((size_t)((g * 32 + jt0 + ji) * 32 + ksabs)) * 512);
    };

    // ---------------- phase 1: x ----------------
    loadW(WA, 0);
    {
        const unsigned short* g = xb + (size_t)(start + stage_row) * HHE + gchunk * 8;
        GLOAD_LDS16(g, &SH[(0 * 3 + 0) * 2048 + wv * 512]);
    }
    __syncthreads();

    auto p1_body = [&](int ks, bf16x8 (&WU)[4][2], bf16x8 (&WP)[4][2], int prefks) {
        const int cur = ks & 1;
        if (ks < 15) {
            const unsigned short* g = xb + (size_t)(start + stage_row) * HHE + (ks + 1) * 32 + gchunk * 8;
            GLOAD_LDS16(g, &SH[((cur ^ 1) * 3 + 0) * 2048 + wv * 512]);
        }
        loadW(WP, prefks);   // prefetch one iteration ahead
        bf16x8 a0 = *(const bf16x8*)&SH[(cur * 3 + 0) * 2048 + (wm * 32 + 0 + ln) * 32 + rdoff];
        bf16x8 a1 = *(const bf16x8*)&SH[(cur * 3 + 0) * 2048 + (wm * 32 + 16 + ln) * 32 + rdoff];
        #pragma unroll
        for (int ji = 0; ji < 2; ++ji) {
            acc_i[0][ji] = MFMA16(a0, WU[0][ji], acc_i[0][ji]);
            acc_i[1][ji] = MFMA16(a1, WU[0][ji], acc_i[1][ji]);
            acc_f[0][ji] = MFMA16(a0, WU[1][ji], acc_f[0][ji]);
            acc_f[1][ji] = MFMA16(a1, WU[1][ji], acc_f[1][ji]);
            acc_o[0][ji] = MFMA16(a0, WU[2][ji], acc_o[0][ji]);
            acc_o[1][ji] = MFMA16(a1, WU[2][ji], acc_o[1][ji]);
            acc_u[0][ji] = MFMA16(a0, WU[3][ji], acc_u[0][ji]);
            acc_u[1][ji] = MFMA16(a1, WU[3][ji], acc_u[1][ji]);
        }
        __syncthreads();
    };

    for (int kk = 0; kk < 8; ++kk) {
        p1_body(2 * kk,     WA, WB, 2 * kk + 1);
        p1_body(2 * kk + 1, WB, WA, (kk == 7) ? 16 : 2 * kk + 2);   // last prefetch = phase2 ks0
    }

    // fork f
    f32x4 acc_fl[2][2], acc_fr[2][2];
    #pragma unroll
    for (int t = 0; t < 2; ++t)
        #pragma unroll
        for (int ji = 0; ji < 2; ++ji) { acc_fl[t][ji] = acc_f[t][ji]; acc_fr[t][ji] = acc_f[t][ji]; }

    // ---------------- phase 2: hsum / h_l / h_r ----------------
    {
        const unsigned short* gs = hs + (size_t)stage_row * HHE + gchunk * 8;
        const unsigned short* gl = hc + ((size_t)(2 * stage_row)) * HHE + gchunk * 8;
        GLOAD_LDS16(gs, &SH[(0 * 3 + 0) * 2048 + wv * 512]);
        GLOAD_LDS16(gl, &SH[(0 * 3 + 1) * 2048 + wv * 512]);
        GLOAD_LDS16(gl + HHE, &SH[(0 * 3 + 2) * 2048 + wv * 512]);
    }
    __syncthreads();

    auto p2_body = [&](int ks, bf16x8 (&WU)[4][2], bf16x8 (&WP)[4][2], int prefks) {
        const int cur = ks & 1;
        if (ks < 15) {
            const unsigned short* gs = hs + (size_t)stage_row * HHE + (ks + 1) * 32 + gchunk * 8;
            const unsigned short* gl = hc + ((size_t)(2 * stage_row)) * HHE + (ks + 1) * 32 + gchunk * 8;
            GLOAD_LDS16(gs, &SH[((cur ^ 1) * 3 + 0) * 2048 + wv * 512]);
            GLOAD_LDS16(gl, &SH[((cur ^ 1) * 3 + 1) * 2048 + wv * 512]);
            GLOAD_LDS16(gl + HHE, &SH[((cur ^ 1) * 3 + 2) * 2048 + wv * 512]);
        }
        loadW(WP, prefks);
        bf16x8 s0 = *(const bf16x8*)&SH[(cur * 3 + 0) * 2048 + (wm * 32 + 0 + ln) * 32 + rdoff];
        bf16x8 s1 = *(const bf16x8*)&SH[(cur * 3 + 0) * 2048 + (wm * 32 + 16 + ln) * 32 + rdoff];
        bf16x8 l0 = *(const bf16x8*)&SH[(cur * 3 + 1) * 2048 + (wm * 32 + 0 + ln) * 32 + rdoff];
        bf16x8 l1 = *(const bf16x8*)&SH[(cur * 3 + 1) * 2048 + (wm * 32 + 16 + ln) * 32 + rdoff];
        bf16x8 r0 = *(const bf16x8*)&SH[(cur * 3 + 2) * 2048 + (wm * 32 + 0 + ln) * 32 + rdoff];
        bf16x8 r1 = *(const bf16x8*)&SH[(cur * 3 + 2) * 2048 + (wm * 32 + 16 + ln) * 32 + rdoff];
        #pragma unroll
        for (int ji = 0; ji < 2; ++ji) {
            acc_i[0][ji]  = MFMA16(s0, WU[0][ji], acc_i[0][ji]);
            acc_i[1][ji]  = MFMA16(s1, WU[0][ji], acc_i[1][ji]);
            acc_o[0][ji]  = MFMA16(s0, WU[2][ji], acc_o[0][ji]);
            acc_o[1][ji]  = MFMA16(s1, WU[2][ji], acc_o[1][ji]);
            acc_u[0][ji]  = MFMA16(s0, WU[3][ji], acc_u[0][ji]);
            acc_u[1][ji]  = MFMA16(s1, WU[3][ji], acc_u[1][ji]);
            acc_fl[0][ji] = MFMA16(l0, WU[1][ji], acc_fl[0][ji]);
            acc_fl[1][ji] = MFMA16(l1, WU[1][ji], acc_fl[1][ji]);
            acc_fr[0][ji] = MFMA16(r0, WU[1][ji], acc_fr[0][ji]);
            acc_fr[1][ji] = MFMA16(r1, WU[1][ji], acc_fr[1][ji]);
        }
        __syncthreads();
    };

    for (int kk = 0; kk < 8; ++kk) {
        p2_body(2 * kk,     WA, WB, 16 + 2 * kk + 1);
        p2_body(2 * kk + 1, WB, WA, (kk == 7) ? 31 : 16 + 2 * kk + 2);  // last: dummy reload
    }

    // ---------------- epilogue ----------------
    #pragma unroll
    for (int ji = 0; ji < 2; ++ji) {
        const int jj = (jt0 + ji) * 16 + ln;
        const float bij = bi[jj], bfj = bfv[jj], boj = bo[jj], buj = bu[jj];
        #pragma unroll
        for (int t = 0; t < 2; ++t) {
            const int n0 = mb + wm * 32 + t * 16 + q * 4;
            float hv[4];
            #pragma unroll
            for (int r = 0; r < 4; ++r) {
                const int node = n0 + r;
                size_t cix = (size_t)(2 * node) * HHE + jj;
                float cl = bf2f(cc[cix]);
                float cr = bf2f(cc[cix + HHE]);
                float gi  = sigf(acc_i[t][ji][r] + bij);
                float gfl = sigf(acc_fl[t][ji][r] + bfj);
                float gfr = sigf(acc_fr[t][ji][r] + bfj);
                float go  = sigf(acc_o[t][ji][r] + boj);
                float gu  = tanhf_(acc_u[t][ji][r] + buj);
                float cnv = gi * gu + gfl * cl + gfr * cr;
                float hnv = go * tanhf_(cnv);
                hv[r] = hnv;
                size_t oix = (size_t)node * HHE + jj;
                hw[oix] = rne_bf16(hnv);
                cw[oix] = rne_bf16(cnv);
            }
            hso[(size_t)(n0 >> 1) * HHE + jj]       = rne_bf16(hv[0] + hv[1]);
            hso[(size_t)((n0 >> 1) + 1) * HHE + jj] = rne_bf16(hv[2] + hv[3]);
        }
    }
}

// ---------- tiny levels (5..0): register kernel, per-level launch; grid = (mchunks, 8) ----------
__global__ __launch_bounds__(256) void level_reg(
    const unsigned short* __restrict__ xb, const unsigned short* __restrict__ wp,
    const float* __restrict__ bi, const float* __restrict__ bfv,
    const float* __restrict__ bo, const float* __restrict__ bu,
    const unsigned short* __restrict__ hc, const unsigned short* __restrict__ cc,
    const unsigned short* __restrict__ hs,
    unsigned short* __restrict__ hw, unsigned short* __restrict__ cw,
    unsigned short* __restrict__ hso,
    float* __restrict__ f32out,
    int start, int cnt)
{
    const int tid  = threadIdx.x;
    const int lane = tid & 63;
    const int wv   = tid >> 6;
    const int quad = lane >> 4;
    const int ln   = lane & 15;
    const int mb   = blockIdx.x * 64;
    const int jt   = blockIdx.y * 4 + wv;
    const int j    = jt * 16 + ln;

    int row[4];
    #pragma unroll
    for (int t = 0; t < 4; ++t) {
        int r = mb + t * 16 + ln;
        row[t] = (r < cnt) ? r : (cnt - 1);
    }
    const unsigned short* ax[4];
    #pragma unroll
    for (int t = 0; t < 4; ++t) ax[t] = xb + (size_t)(start + row[t]) * HHE + quad * 8;

    const unsigned short* bw[4];
    #pragma unroll
    for (int g = 0; g < 4; ++g) bw[g] = wp + ((size_t)(g * 32 + jt) * 32) * 512 + lane * 8;

    f32x4 zero = {0.f, 0.f, 0.f, 0.f};
    f32x4 acc_i[4], acc_f[4], acc_o[4], acc_u[4];
    #pragma unroll
    for (int t = 0; t < 4; ++t) { acc_i[t] = zero; acc_f[t] = zero; acc_o[t] = zero; acc_u[t] = zero; }

    #pragma unroll 4
    for (int ks = 0; ks < 16; ++ks) {
        bf16x8 a[4];
        #pragma unroll
        for (int t = 0; t < 4; ++t) { a[t] = *(const bf16x8*)ax[t]; ax[t] += 32; }
        bf16x8 b0 = *(const bf16x8*)bw[0]; bw[0] += 512;
        bf16x8 b1 = *(const bf16x8*)bw[1]; bw[1] += 512;
        bf16x8 b2 = *(const bf16x8*)bw[2]; bw[2] += 512;
        bf16x8 b3 = *(const bf16x8*)bw[3]; bw[3] += 512;
        #pragma unroll
        for (int t = 0; t < 4; ++t) {
            acc_i[t] = MFMA16(a[t], b0, acc_i[t]);
            acc_f[t] = MFMA16(a[t], b1, acc_f[t]);
            acc_o[t] = MFMA16(a[t], b2, acc_o[t]);
            acc_u[t] = MFMA16(a[t], b3, acc_u[t]);
        }
    }

    f32x4 acc_fl[4], acc_fr[4];
    #pragma unroll
    for (int t = 0; t < 4; ++t) { acc_fl[t] = acc_f[t]; acc_fr[t] = acc_f[t]; }

    const unsigned short* as[4];
    const unsigned short* al[4];
    const unsigned short* ar[4];
    #pragma unroll
    for (int t = 0; t < 4; ++t) {
        as[t] = hs + (size_t)row[t] * HHE + quad * 8;
        al[t] = hc + (size_t)(2 * row[t]) * HHE + quad * 8;
        ar[t] = al[t] + HHE;
    }

    #pragma unroll 2
    for (int ks = 0; ks < 16; ++ks) {
        bf16x8 b0 = *(const bf16x8*)bw[0]; bw[0] += 512;
        bf16x8 b1 = *(const bf16x8*)bw[1]; bw[1] += 512;
        bf16x8 b2 = *(const bf16x8*)bw[2]; bw[2] += 512;
        bf16x8 b3 = *(const bf16x8*)bw[3]; bw[3] += 512;
        bf16x8 s[4];
        #pragma unroll
        for (int t = 0; t < 4; ++t) { s[t] = *(const bf16x8*)as[t]; as[t] += 32; }
        #pragma unroll
        for (int t = 0; t < 4; ++t) {
            acc_i[t] = MFMA16(s[t], b0, acc_i[t]);
            acc_o[t] = MFMA16(s[t], b2, acc_o[t]);
            acc_u[t] = MFMA16(s[t], b3, acc_u[t]);
        }
        bf16x8 l[4];
        #pragma unroll
        for (int t = 0; t < 4; ++t) { l[t] = *(const bf16x8*)al[t]; al[t] += 32; }
        #pragma unroll
        for (int t = 0; t < 4; ++t) acc_fl[t] = MFMA16(l[t], b1, acc_fl[t]);
        bf16x8 rr[4];
        #pragma unroll
        for (int t = 0; t < 4; ++t) { rr[t] = *(const bf16x8*)ar[t]; ar[t] += 32; }
        #pragma unroll
        for (int t = 0; t < 4; ++t) acc_fr[t] = MFMA16(rr[t], b1, acc_fr[t]);
    }

    const float bij = bi[j], bfj = bfv[j], boj = bo[j], buj = bu[j];
    #pragma unroll
    for (int t = 0; t < 4; ++t) {
        const int n0 = mb + t * 16 + quad * 4;
        float hv[4];
        #pragma unroll
        for (int r = 0; r < 4; ++r) {
            const int node = n0 + r;
            const int ncl  = (node < cnt) ? node : (cnt - 1);
            size_t cix = (size_t)(2 * ncl) * HHE + j;
            float cl = bf2f(cc[cix]);
            float cr = bf2f(cc[cix + HHE]);
            float gi  = sigf(acc_i[t][r] + bij);
            float gfl = sigf(acc_fl[t][r] + bfj);
            float gfr = sigf(acc_fr[t][r] + bfj);
            float go  = sigf(acc_o[t][r] + boj);
            float gu  = tanhf_(acc_u[t][r] + buj);
            float cnv = gi * gu + gfl * cl + gfr * cr;
            float hnv = go * tanhf_(cnv);
            hv[r] = hnv;
            if (node < cnt) {
                size_t oix = (size_t)node * HHE + j;
                hw[oix] = rne_bf16(hnv);
                cw[oix] = rne_bf16(cnv);
                if (f32out) {
                    f32out[(size_t)node * 1024 + j]       = hnv;
                    f32out[(size_t)node * 1024 + 512 + j] = cnv;
                }
            }
        }
        if (n0 + 1 < cnt) hso[(size_t)(n0 >> 1) * HHE + j]       = rne_bf16(hv[0] + hv[1]);
        if (n0 + 3 < cnt) hso[(size_t)((n0 >> 1) + 1) * HHE + j] = rne_bf16(hv[2] + hv[3]);
    }
}

extern "C" void kernel_launch(void* const* d_in, const int* in_sizes, int n_in,
                              void* d_out, int out_size, void* d_ws, size_t ws_size,
                              hipStream_t stream) {
    const float* x  = (const float*)d_in[0];
    const float* Wi = (const float*)d_in[1];
    const float* bi = (const float*)d_in[2];
    const float* Wf = (const float*)d_in[3];
    const float* bf = (const float*)d_in[4];
    const float* Wo = (const float*)d_in[5];
    const float* bo = (const float*)d_in[6];
    const float* Wu = (const float*)d_in[7];
    const float* bu = (const float*)d_in[8];
    float* out = (float*)d_out;

    unsigned short* xb  = (unsigned short*)d_ws;          // x bf16
    unsigned short* wp  = xb  + 16776704;                 // packed W bf16
    unsigned short* hA  = wp  + 2097152;                  // h ping (16384 rows)
    unsigned short* hB  = hA  + 8388608;                  // h pong ( 8192 rows)
    unsigned short* hs1 = hB  + 4194304;                  // hsum ( 8192 rows)
    unsigned short* hs2 = hs1 + 4194304;                  // hsum ( 4096 rows)
    unsigned short* cA  = hs2 + 2097152;                  // c ping
    unsigned short* cB  = cA  + 8388608;                  // c pong

    pack_w<<<1024, 256, 0, stream>>>(Wi, Wf, Wo, Wu, wp);
    conv_x<<<8192, 256, 0, stream>>>(x, xb);

    // leaf: grid (m=256, j=8) m-major -> A shared across j within an XCD
    leaf_mfma<<<dim3(256, 8), 256, 0, stream>>>(xb, wp, bi, bo, bu, hA, cA, hs1, 16383, 16384);

    // levels 13..6 (cnt >= 64): LDS-staged kernel with W register prefetch
    for (int lvl = 13; lvl >= 6; --lvl) {
        int cnt   = 1 << lvl;
        int start = cnt - 1;
        const unsigned short *hc, *cc, *hs;
        unsigned short *hw, *cw, *hso;
        if (lvl & 1) { hc = hA; cc = cA; hs = hs1; hw = hB; cw = cB; hso = hs2; }
        else         { hc = hB; cc = cB; hs = hs2; hw = hA; cw = cA; hso = hs1; }
        level_v3<<<dim3(cnt / 64, 8), 256, 0, stream>>>(xb, wp, bi, bf, bo, bu,
                                                        hc, cc, hs, hw, cw, hso, start, cnt);
    }

    // levels 5..0: register kernel
    for (int lvl = 5; lvl >= 0; --lvl) {
        int cnt   = 1 << lvl;
        int start = cnt - 1;
        const unsigned short *hc, *cc, *hs;
        unsigned short *hw, *cw, *hso;
        if (lvl & 1) { hc = hA; cc = cA; hs = hs1; hw = hB; cw = cB; hso = hs2; }
        else         { hc = hB; cc = cB; hs = hs2; hw = hA; cw = cA; hso = hs1; }
        float* f32out = (lvl == 0) ? out : nullptr;
        level_reg<<<dim3(1, 8), 256, 0, stream>>>(xb, wp, bi, bf, bo, bu,
                                                  hc, cc, hs, hw, cw, hso, f32out,
                                                  start, cnt);
    }
}